// Round 1
// baseline (756.443 us; speedup 1.0000x reference)
//
#include <hip/hip_runtime.h>
#include <math.h>

// Problem constants (fixed by setup_inputs)
constexpr int B = 16, T = 800, V = 4000, L = 100;
constexpr int S = 2 * L + 1;      // 201 extended states
constexpr float NEGV = -1e30f;
constexpr float LAMB = 0.1f;

__device__ __forceinline__ float lae(float a, float b) {
    float m = fmaxf(a, b);
    float d = fminf(a, b) - m;          // <= 0, finite (NEGV not -inf)
    return m + log1pf(__expf(d));
}

// Kernel 1: per-row (b,t) logsumexp over V, plus gather of emission
// log-probs at blank + L labels into emit[B*T][L+1].
__global__ __launch_bounds__(256) void lse_emit_kernel(
        const float* __restrict__ logits, const int* __restrict__ labels,
        float* __restrict__ lse_arr, float* __restrict__ emit) {
    const int row = blockIdx.x;              // b*T + t
    const int b = row / T;
    const float* __restrict__ rp = logits + (size_t)row * V;
    const int tid = threadIdx.x;
    const int wid = tid >> 6, lane = tid & 63;

    // pass 1: row max (vectorized, V % 4 == 0, row base 16B-aligned)
    const float4* rp4 = (const float4*)rp;
    float m = -INFINITY;
    for (int i = tid; i < V / 4; i += 256) {
        float4 x = rp4[i];
        m = fmaxf(m, fmaxf(fmaxf(x.x, x.y), fmaxf(x.z, x.w)));
    }
    #pragma unroll
    for (int off = 32; off > 0; off >>= 1) m = fmaxf(m, __shfl_down(m, off, 64));
    __shared__ float sm[4], ss[4], s_lse;
    if (lane == 0) sm[wid] = m;
    __syncthreads();
    m = fmaxf(fmaxf(sm[0], sm[1]), fmaxf(sm[2], sm[3]));

    // pass 2: sum exp(x - m) (row is hot in L1/L2)
    float s = 0.f;
    for (int i = tid; i < V / 4; i += 256) {
        float4 x = rp4[i];
        s += __expf(x.x - m) + __expf(x.y - m) + __expf(x.z - m) + __expf(x.w - m);
    }
    #pragma unroll
    for (int off = 32; off > 0; off >>= 1) s += __shfl_down(s, off, 64);
    if (lane == 0) ss[wid] = s;
    __syncthreads();
    if (tid == 0) {
        float l = m + logf(ss[0] + ss[1] + ss[2] + ss[3]);
        lse_arr[row] = l;
        s_lse = l;
    }
    __syncthreads();
    float l = s_lse;

    // gather emissions: index 0 = blank(v=0), index 1+j = labels[b][j]
    if (tid <= L) {
        int v = (tid == 0) ? 0 : labels[b * L + tid - 1];
        emit[(size_t)row * (L + 1) + tid] = rp[v] - l;
    }
}

// Kernel 2: per-batch CTC forward DP over S=201 states + denominator sum.
__global__ __launch_bounds__(256) void ctc_dp_kernel(
        const float* __restrict__ lse_arr, const float* __restrict__ emit,
        const int* __restrict__ labels, const int* __restrict__ in_len,
        const int* __restrict__ lab_len, float* __restrict__ costs) {
    const int b = blockIdx.x;
    const int tid = threadIdx.x;
    const int wid = tid >> 6, lane = tid & 63;
    const int len = in_len[b];
    const int lb = lab_len[b];

    // denominator: sum_{t < len} lse[b,t]
    float d = 0.f;
    for (int t = tid; t < len; t += 256) d += lse_arr[b * T + t];
    #pragma unroll
    for (int off = 32; off > 0; off >>= 1) d += __shfl_down(d, off, 64);
    __shared__ float sred[4];
    if (lane == 0) sred[wid] = d;

    // DP state
    __shared__ float bufA[256], bufB[256];
    const int s = tid;
    const int k = (s & 1) ? (1 + (s >> 1)) : 0;   // emit column for state s
    bool allow = false;
    if ((s & 1) && s >= 3 && s < S)
        allow = labels[b * L + (s >> 1)] != labels[b * L + (s >> 1) - 1];
    const float* __restrict__ eb = emit + (size_t)b * T * (L + 1);

    // t = 0 init
    float a0 = NEGV;
    if (s == 0) a0 = eb[0];
    else if (s == 1) a0 = eb[1];
    bufA[tid] = (s < S) ? a0 : NEGV;
    __syncthreads();

    float* cur = bufA;
    float* nxt = bufB;
    // prefetch emission for t = 1
    float e = (len > 1 && s < S) ? eb[(size_t)(L + 1) + k] : 0.f;
    for (int t = 1; t < len; ++t) {
        float a  = cur[tid];
        float a1 = (tid >= 1) ? cur[tid - 1] : NEGV;
        float a2 = allow ? cur[tid - 2] : NEGV;      // allow implies tid >= 3
        float nv = lae(lae(a, a1), a2) + e;
        if (s >= S) nv = NEGV;
        if (t + 1 < len && s < S)                     // prefetch next step
            e = eb[(size_t)(t + 1) * (L + 1) + k];
        nxt[tid] = nv;
        __syncthreads();
        float* tmp = cur; cur = nxt; nxt = tmp;
    }

    if (tid == 0) {
        float den = sred[0] + sred[1] + sred[2] + sred[3];
        int end = 2 * lb;                             // lb >= 1 -> end >= 2
        float nll = -lae(cur[end], cur[end - 1]);
        costs[b] = den - (1.0f + LAMB) * nll;
    }
}

// Kernel 3: mean over batch
__global__ void finalize_kernel(const float* __restrict__ costs,
                                float* __restrict__ out) {
    int tid = threadIdx.x;     // 64 threads
    float c = (tid < B) ? costs[tid] : 0.f;
    #pragma unroll
    for (int off = 32; off > 0; off >>= 1) c += __shfl_down(c, off, 64);
    if (tid == 0) out[0] = c / (float)B;
}

extern "C" void kernel_launch(void* const* d_in, const int* in_sizes, int n_in,
                              void* d_out, int out_size, void* d_ws, size_t ws_size,
                              hipStream_t stream) {
    const float* logits  = (const float*)d_in[0];
    const int*   labels  = (const int*)d_in[1];
    const int*   in_len  = (const int*)d_in[2];
    const int*   lab_len = (const int*)d_in[3];
    float* out = (float*)d_out;

    // workspace layout (floats): lse[B*T] | emit[B*T*(L+1)] | costs[B]  (~5.2 MB)
    float* lse_arr = (float*)d_ws;
    float* emit    = lse_arr + B * T;
    float* costs   = emit + (size_t)B * T * (L + 1);

    lse_emit_kernel<<<B * T, 256, 0, stream>>>(logits, labels, lse_arr, emit);
    ctc_dp_kernel<<<B, 256, 0, stream>>>(lse_arr, emit, labels, in_len, lab_len, costs);
    finalize_kernel<<<1, 64, 0, stream>>>(costs, out);
}

// Round 2
// 690.080 us; speedup vs baseline: 1.0962x; 1.0962x over previous
//
#include <hip/hip_runtime.h>
#include <math.h>

// Problem constants (fixed by setup_inputs)
constexpr int B = 16, T = 800, V = 4000, L = 100;
constexpr int S = 2 * L + 1;      // 201 extended states
constexpr float NEGV = -1e30f;
constexpr float LAMB = 0.1f;

__device__ __forceinline__ float lae2(float a, float b) {
    float m = fmaxf(a, b);
    float d = fminf(a, b) - m;                 // <= 0, finite
    return m + __logf(1.f + __expf(d));
}
__device__ __forceinline__ float lae3(float a, float b, float c) {
    float m = fmaxf(fmaxf(a, b), c);           // v_max3
    float s = __expf(a - m) + __expf(b - m) + __expf(c - m);
    return m + __logf(s);
}

// Kernel 1: one WAVE per (b,t) row. Single-pass online logsumexp over V,
// butterfly combine, then gather emissions at the b's labels (+blank).
// emit_lab[row*L + j] = logit[labels[b,j]] - lse ; emit_blank[row] = logit[0]-lse.
__global__ __launch_bounds__(256) void lse_emit_kernel(
        const float* __restrict__ logits, const int* __restrict__ labels,
        float* __restrict__ lse_arr, float* __restrict__ emit_lab,
        float* __restrict__ emit_blank) {
    const int w = threadIdx.x >> 6, lane = threadIdx.x & 63;
    const int row = blockIdx.x * 4 + w;        // B*T = 12800 = 3200*4 exact
    const int b = row / T;
    const float* __restrict__ rp = logits + (size_t)row * V;
    const float4* __restrict__ rp4 = (const float4*)rp;

    float m = -INFINITY, s = 0.f;
    for (int i = lane; i < V / 4; i += 64) {   // 1000 float4s
        float4 x = rp4[i];
        float xm = fmaxf(fmaxf(x.x, x.y), fmaxf(x.z, x.w));
        float nm = fmaxf(m, xm);
        s = s * __expf(m - nm)
          + __expf(x.x - nm) + __expf(x.y - nm)
          + __expf(x.z - nm) + __expf(x.w - nm);
        m = nm;
    }
    #pragma unroll
    for (int k = 1; k < 64; k <<= 1) {         // butterfly (m,s) combine
        float om = __shfl_xor(m, k);
        float os = __shfl_xor(s, k);
        float nm = fmaxf(m, om);
        s = s * __expf(m - nm) + os * __expf(om - nm);
        m = nm;
    }
    float lse = m + __logf(s);

    if (lane < L / 2) {                        // lanes 0..49: labels 2l, 2l+1
        int2 lab = *(const int2*)(labels + b * L + 2 * lane);
        float2 o = make_float2(rp[lab.x] - lse, rp[lab.y] - lse);
        *(float2*)(emit_lab + (size_t)row * L + 2 * lane) = o;
    } else if (lane == 50) {
        emit_blank[row] = rp[0] - lse;
    } else if (lane == 51) {
        lse_arr[row] = lse;
    }
}

// Kernel 2: per-batch CTC forward DP, ONE WAVE, alpha entirely in registers.
// Lane l holds states s = 4l..4l+3. The only cross-lane dep per step is the
// previous lane's a3 (covers s-1 for state 4l and s-2 for state 4l+1).
__global__ __launch_bounds__(64) void ctc_dp_kernel(
        const float* __restrict__ lse_arr, const float* __restrict__ emit_lab,
        const float* __restrict__ emit_blank, const int* __restrict__ labels,
        const int* __restrict__ in_len, const int* __restrict__ lab_len,
        float* __restrict__ costs) {
    const int b = blockIdx.x;
    const int l = threadIdx.x;                 // lane 0..63
    const int len = in_len[b];
    const int lb = lab_len[b];

    // denominator: sum_{t<len} lse[b,t], butterfly so all lanes hold it
    float den = 0.f;
    for (int t = l; t < len; t += 64) den += lse_arr[b * T + t];
    #pragma unroll
    for (int k = 1; k < 64; k <<= 1) den += __shfl_xor(den, k);

    // per-lane static data
    int lab0 = -1, lab1 = -2;                  // labels at idx 2l, 2l+1
    if (2 * l < L)     lab0 = labels[b * L + 2 * l];
    if (2 * l + 1 < L) lab1 = labels[b * L + 2 * l + 1];
    int labm1 = __shfl_up(lab1, 1);            // labels[2l-1] from prev lane
    const bool allow1 = (l >= 1) && (lab0 != labm1);   // state 4l+1 skip
    const bool allow3 = (lab1 != lab0);                 // state 4l+3 skip
    const int s0 = 4 * l;
    const bool v0 = s0 < S, v1 = s0 + 1 < S, v2 = s0 + 2 < S, v3 = s0 + 3 < S;

    const float* __restrict__ ebB = emit_blank + b * T;
    const float* __restrict__ ebL = emit_lab + (size_t)b * T * L;
    const bool hasL = (l < L / 2);             // lanes 0..49 load float2

    // t = 0 init: alpha[0]=blank emit, alpha[1]=label0 emit, rest NEGV
    float a0 = (l == 0) ? ebB[0] : NEGV;
    float a1 = (l == 0) ? ebL[0] : NEGV;
    float a2 = NEGV, a3 = NEGV;

    // depth-4 emission prefetch ring (hides L2 latency; no barriers anywhere)
    float2 pL[4]; float pB[4];
    #pragma unroll
    for (int p = 0; p < 4; ++p) {
        int tc = min(1 + p, len - 1);
        pL[p] = hasL ? *(const float2*)(ebL + (size_t)tc * L + 2 * l)
                     : make_float2(NEGV, NEGV);
        pB[p] = ebB[tc];
    }

    #pragma unroll 4
    for (int t = 1; t < len; ++t) {
        const int c = (t - 1) & 3;
        float2 eL = pL[c]; float eB = pB[c];
        int tc = min(t + 4, len - 1);          // refill same slot
        pL[c] = hasL ? *(const float2*)(ebL + (size_t)tc * L + 2 * l)
                     : make_float2(NEGV, NEGV);
        pB[c] = ebB[tc];

        float pa3 = __shfl_up(a3, 1);          // prev lane's state 4l-1
        if (l == 0) pa3 = NEGV;
        float n0 = lae2(a0, pa3) + eB;                          // s=4l (blank)
        float n1 = lae3(a1, a0, allow1 ? pa3 : NEGV) + eL.x;    // s=4l+1
        float n2 = lae2(a2, a1) + eB;                           // s=4l+2 (blank)
        float n3 = lae3(a3, a2, allow3 ? a1 : NEGV) + eL.y;     // s=4l+3
        a0 = v0 ? n0 : NEGV;
        a1 = v1 ? n1 : NEGV;
        a2 = v2 ? n2 : NEGV;
        a3 = v3 ? n3 : NEGV;
    }

    // gather final alpha at states end=2*lb and end-1 via LDS (single wave)
    __shared__ float sa[256];
    sa[s0] = a0; sa[s0 + 1] = a1; sa[s0 + 2] = a2; sa[s0 + 3] = a3;
    __syncthreads();
    if (l == 0) {
        int end = 2 * lb;                      // lb >= 1 -> end >= 2
        float nll = -lae2(sa[end], sa[end - 1]);
        costs[b] = den - (1.0f + LAMB) * nll;
    }
}

// Kernel 3: mean over batch
__global__ void finalize_kernel(const float* __restrict__ costs,
                                float* __restrict__ out) {
    int tid = threadIdx.x;                     // 64 threads
    float c = (tid < B) ? costs[tid] : 0.f;
    #pragma unroll
    for (int off = 32; off > 0; off >>= 1) c += __shfl_down(c, off, 64);
    if (tid == 0) out[0] = c / (float)B;
}

extern "C" void kernel_launch(void* const* d_in, const int* in_sizes, int n_in,
                              void* d_out, int out_size, void* d_ws, size_t ws_size,
                              hipStream_t stream) {
    const float* logits  = (const float*)d_in[0];
    const int*   labels  = (const int*)d_in[1];
    const int*   in_len  = (const int*)d_in[2];
    const int*   lab_len = (const int*)d_in[3];
    float* out = (float*)d_out;

    // ws layout (floats): lse[B*T] | emit_lab[B*T*L] | emit_blank[B*T] | costs[B]
    float* lse_arr    = (float*)d_ws;
    float* emit_lab   = lse_arr + B * T;
    float* emit_blank = emit_lab + (size_t)B * T * L;
    float* costs      = emit_blank + B * T;

    lse_emit_kernel<<<B * T / 4, 256, 0, stream>>>(logits, labels, lse_arr,
                                                   emit_lab, emit_blank);
    ctc_dp_kernel<<<B, 64, 0, stream>>>(lse_arr, emit_lab, emit_blank, labels,
                                        in_len, lab_len, costs);
    finalize_kernel<<<1, 64, 0, stream>>>(costs, out);
}

// Round 3
// 434.245 us; speedup vs baseline: 1.7420x; 1.5891x over previous
//
#include <hip/hip_runtime.h>
#include <math.h>

// Problem constants (fixed by setup_inputs)
constexpr int B = 16, T = 800, V = 4000, L = 100;
constexpr int S = 2 * L + 1;      // 201 extended states
constexpr int EST = 104;          // emission row stride (floats): [0..99]=labels, [100]=blank
constexpr float NEGV = -1e30f;
constexpr float LAMB = 0.1f;
constexpr float LOG2E = 1.4426950408889634f;
constexpr float LN2 = 0.6931471805599453f;

typedef float f32x4 __attribute__((ext_vector_type(4)));

__device__ __forceinline__ float fexp2(float x) {
#if __has_builtin(__builtin_amdgcn_exp2f)
    return __builtin_amdgcn_exp2f(x);
#else
    return __expf(x * LN2);
#endif
}

// log2-domain logaddexp: all deltas <= 0 by construction (no overflow/NaN)
__device__ __forceinline__ float l2ae2(float a, float b) {
    float m = fmaxf(a, b);
    float d = fminf(a, b) - m;
    return m + __log2f(1.f + fexp2(d));
}
__device__ __forceinline__ float l2ae3(float a, float b, float c) {
    float m = fmaxf(fmaxf(a, b), c);
    float s = fexp2(a - m) + fexp2(b - m) + fexp2(c - m);
    return m + __log2f(s);
}

// Kernel 1: one WAVE per (b,t) row. Online logsumexp over V with two
// independent (m,s) accumulators, butterfly combine, then emission gather.
// emit_all[row*EST + j] = (logit[lab_j] - lse)*log2e ; [100] = blank emission.
__global__ __launch_bounds__(256) void lse_emit_kernel(
        const float* __restrict__ logits, const int* __restrict__ labels,
        float* __restrict__ lse_arr, float* __restrict__ emit_all) {
    const int w = threadIdx.x >> 6, lane = threadIdx.x & 63;
    const int row = blockIdx.x * 4 + w;        // B*T = 12800 = 3200*4 exact
    const int b = row / T;
    const float* __restrict__ rp = logits + (size_t)row * V;
    const f32x4* __restrict__ rp4 = (const f32x4*)rp;

    float m0 = -INFINITY, s0 = 0.f, m1 = -INFINITY, s1 = 0.f;
    for (int i = lane; i < 500; i += 64) {     // first half of 1000 float4s
        f32x4 x = __builtin_nontemporal_load(rp4 + i);
        float xm = fmaxf(fmaxf(x.x, x.y), fmaxf(x.z, x.w));
        float nm = fmaxf(m0, xm);
        s0 = s0 * __expf(m0 - nm)
           + __expf(x.x - nm) + __expf(x.y - nm)
           + __expf(x.z - nm) + __expf(x.w - nm);
        m0 = nm;
    }
    for (int i = 500 + lane; i < 1000; i += 64) {  // second half
        f32x4 x = __builtin_nontemporal_load(rp4 + i);
        float xm = fmaxf(fmaxf(x.x, x.y), fmaxf(x.z, x.w));
        float nm = fmaxf(m1, xm);
        s1 = s1 * __expf(m1 - nm)
           + __expf(x.x - nm) + __expf(x.y - nm)
           + __expf(x.z - nm) + __expf(x.w - nm);
        m1 = nm;
    }
    float m = fmaxf(m0, m1);
    float s = s0 * __expf(m0 - m) + s1 * __expf(m1 - m);
    #pragma unroll
    for (int k = 1; k < 64; k <<= 1) {         // butterfly (m,s) combine
        float om = __shfl_xor(m, k);
        float os = __shfl_xor(s, k);
        float nm = fmaxf(m, om);
        s = s * __expf(m - nm) + os * __expf(om - nm);
        m = nm;
    }
    float lse = m + __logf(s);

    if (lane < L / 2) {                        // lanes 0..49: labels 2l, 2l+1
        int2 lab = *(const int2*)(labels + b * L + 2 * lane);
        float2 o = make_float2((rp[lab.x] - lse) * LOG2E,
                               (rp[lab.y] - lse) * LOG2E);
        *(float2*)(emit_all + (size_t)row * EST + 2 * lane) = o;
    } else if (lane == 50) {
        emit_all[(size_t)row * EST + 100] = (rp[0] - lse) * LOG2E;
    } else if (lane == 51) {
        lse_arr[row] = lse;
    }
}

// One DP time-step: lane l holds states 4l..4l+3 (log2 domain).
// Only cross-lane dep is prev lane's a3 (one ds_bpermute per step).
#define DPSTEP(Q, R) do {                                            \
    float pa3 = __shfl_up(a3, 1);                                    \
    pa3 = (l == 0) ? NEGV : pa3;                                     \
    float n0 = l2ae2(a0, pa3) + (R);                                 \
    float n1 = l2ae3(a1, a0, allow1 ? pa3 : NEGV) + (Q).x;           \
    float n2 = l2ae2(a2, a1) + (R);                                  \
    float n3 = l2ae3(a3, a2, allow3 ? a1 : NEGV) + (Q).y;            \
    a0 = n0; a1 = n1; a2 = n2; a3 = n3; } while (0)

// Refill one named prefetch slot for time TC (clamped; redundant loads ok)
#define REFILL(Q, R, TC) do {                                        \
    int u_ = (TC); u_ = (u_ < len) ? u_ : (len - 1);                 \
    const float* er_ = eA + u_ * EST;                                \
    (Q) = *(const float2*)(er_ + loff);                              \
    (R) = er_[100]; } while (0)

// Kernel 2: per-batch CTC forward DP, ONE WAVE, alpha in registers,
// depth-8 register prefetch ring with NAMED slots (no arrays -> no scratch).
__global__ __launch_bounds__(64) void ctc_dp_kernel(
        const float* __restrict__ lse_arr, const float* __restrict__ emit_all,
        const int* __restrict__ labels, const int* __restrict__ in_len,
        const int* __restrict__ lab_len, float* __restrict__ costs) {
    const int b = blockIdx.x;
    const int l = threadIdx.x;                 // lane 0..63
    const int len = in_len[b];                 // in [400, 800]
    const int lb = lab_len[b];

    // denominator: sum_{t<len} lse[b,t] (natural log), butterfly
    float den = 0.f;
    for (int t = l; t < len; t += 64) den += lse_arr[b * T + t];
    #pragma unroll
    for (int k = 1; k < 64; k <<= 1) den += __shfl_xor(den, k);

    // per-lane static data
    int lab0 = -1, lab1 = -2;
    if (l < L / 2) {
        int2 lab = *(const int2*)(labels + b * L + 2 * l);
        lab0 = lab.x; lab1 = lab.y;
    }
    int labm1 = __shfl_up(lab1, 1);            // labels[2l-1] from prev lane
    const bool allow1 = (l >= 1) && (lab0 != labm1);   // state 4l+1 skip
    const bool allow3 = (lab1 != lab0);                 // state 4l+3 skip
    const int loff = (l < L / 2) ? 2 * l : 0;  // lanes >=50: garbage reads,
                                               // their states never reach valid ones
    const float* __restrict__ eA = emit_all + (size_t)b * T * EST;

    // t = 0 init (log2 domain): alpha[0]=blank, alpha[1]=label0
    float a0 = (l == 0) ? eA[100] : NEGV;
    float a1 = (l == 0) ? eA[0]   : NEGV;
    float a2 = NEGV, a3 = NEGV;

    // prime depth-8 ring (len >= 400 so t=1..8 all valid)
    float2 q0, q1, q2, q3, q4, q5, q6, q7;
    float  r0, r1, r2, r3, r4, r5, r6, r7;
    REFILL(q0, r0, 1); REFILL(q1, r1, 2); REFILL(q2, r2, 3); REFILL(q3, r3, 4);
    REFILL(q4, r4, 5); REFILL(q5, r5, 6); REFILL(q6, r6, 7); REFILL(q7, r7, 8);

    int t = 1;
    for (; t + 7 < len; t += 8) {
        DPSTEP(q0, r0); REFILL(q0, r0, t + 8);
        DPSTEP(q1, r1); REFILL(q1, r1, t + 9);
        DPSTEP(q2, r2); REFILL(q2, r2, t + 10);
        DPSTEP(q3, r3); REFILL(q3, r3, t + 11);
        DPSTEP(q4, r4); REFILL(q4, r4, t + 12);
        DPSTEP(q5, r5); REFILL(q5, r5, t + 13);
        DPSTEP(q6, r6); REFILL(q6, r6, t + 14);
        DPSTEP(q7, r7); REFILL(q7, r7, t + 15);
    }
    // tail: up to 7 steps, wave-uniform branches
    if (t < len) { DPSTEP(q0, r0); ++t; }
    if (t < len) { DPSTEP(q1, r1); ++t; }
    if (t < len) { DPSTEP(q2, r2); ++t; }
    if (t < len) { DPSTEP(q3, r3); ++t; }
    if (t < len) { DPSTEP(q4, r4); ++t; }
    if (t < len) { DPSTEP(q5, r5); ++t; }
    if (t < len) { DPSTEP(q6, r6); ++t; }

    // gather final alpha at states end, end-1
    __shared__ float sa[256];
    sa[4 * l] = a0; sa[4 * l + 1] = a1; sa[4 * l + 2] = a2; sa[4 * l + 3] = a3;
    __syncthreads();
    if (l == 0) {
        int end = 2 * lb;                      // lb >= 1 -> end >= 2
        float nll = -LN2 * l2ae2(sa[end], sa[end - 1]);
        costs[b] = den - (1.0f + LAMB) * nll;
    }
}

// Kernel 3: mean over batch
__global__ void finalize_kernel(const float* __restrict__ costs,
                                float* __restrict__ out) {
    int tid = threadIdx.x;                     // 64 threads
    float c = (tid < B) ? costs[tid] : 0.f;
    #pragma unroll
    for (int off = 32; off > 0; off >>= 1) c += __shfl_down(c, off, 64);
    if (tid == 0) out[0] = c / (float)B;
}

extern "C" void kernel_launch(void* const* d_in, const int* in_sizes, int n_in,
                              void* d_out, int out_size, void* d_ws, size_t ws_size,
                              hipStream_t stream) {
    const float* logits  = (const float*)d_in[0];
    const int*   labels  = (const int*)d_in[1];
    const int*   in_len  = (const int*)d_in[2];
    const int*   lab_len = (const int*)d_in[3];
    float* out = (float*)d_out;

    // ws layout (floats): emit_all[B*T*EST] | lse[B*T] | costs[B]  (~5.4 MB)
    float* emit_all = (float*)d_ws;
    float* lse_arr  = emit_all + (size_t)B * T * EST;
    float* costs    = lse_arr + B * T;

    lse_emit_kernel<<<B * T / 4, 256, 0, stream>>>(logits, labels, lse_arr, emit_all);
    ctc_dp_kernel<<<B, 64, 0, stream>>>(lse_arr, emit_all, labels, in_len, lab_len, costs);
    finalize_kernel<<<1, 64, 0, stream>>>(costs, out);
}